// Round 17
// baseline (431.567 us; speedup 1.0000x reference)
//
#include <hip/hip_runtime.h>
#include <hip/hip_bf16.h>
#include <hip/hip_fp16.h>

#define N_NODES 50000
#define N_EDGES 800000
#define IN_CH 64
#define EDGE_DIM 8
#define HIDDEN 128
#define NUM_GRAPHS 256
#define NPASS 2
#define PASS_W ((N_NODES + NPASS - 1) / NPASS)   // 25000

typedef __attribute__((ext_vector_type(8))) _Float16 half8;
typedef __attribute__((ext_vector_type(4))) float floatx4;

static __device__ __forceinline__ __half2 u2h(int u) {
    union { int i; __half2 h; } cv; cv.i = u; return cv.h;
}

// ===========================================================================
// CSR build: histogram, scan, 2 dst-range eid-scatter passes (write locality),
// then a wave-per-node RANK sort fused with record materialization.
// ===========================================================================
__global__ __launch_bounds__(256) void hist_kernel(
    const int* __restrict__ dst, int* __restrict__ deg, int E)
{
    int i = blockIdx.x * blockDim.x + threadIdx.x;
    if (i < E) atomicAdd(&deg[dst[i]], 1);
}

__global__ __launch_bounds__(256) void scan1_kernel(
    const int* __restrict__ deg, int* __restrict__ incl,
    int* __restrict__ blockSums, int N)
{
    __shared__ int s[256];
    int b = blockIdx.x, t = threadIdx.x;
    int i0 = b * 512 + 2 * t;
    int a0 = (i0 < N) ? deg[i0] : 0;
    int a1 = (i0 + 1 < N) ? deg[i0 + 1] : 0;
    int ps = a0 + a1;
    s[t] = ps;
    __syncthreads();
    for (int off = 1; off < 256; off <<= 1) {
        int v = (t >= off) ? s[t - off] : 0;
        __syncthreads();
        s[t] += v;
        __syncthreads();
    }
    int exclp = s[t] - ps;
    if (i0 < N)     incl[i0]     = exclp + a0;
    if (i0 + 1 < N) incl[i0 + 1] = exclp + a0 + a1;
    if (t == 255) blockSums[b] = s[255];
}

__global__ __launch_bounds__(128) void scan2_kernel(int* __restrict__ blockSums, int B)
{
    __shared__ int s[128];
    int t = threadIdx.x;
    int v = (t < B) ? blockSums[t] : 0;
    s[t] = v;
    __syncthreads();
    for (int off = 1; off < 128; off <<= 1) {
        int u = (t >= off) ? s[t - off] : 0;
        __syncthreads();
        s[t] += u;
        __syncthreads();
    }
    if (t < B) blockSums[t] = s[t] - v;   // exclusive
}

__global__ __launch_bounds__(256) void scan3_kernel(
    const int* __restrict__ incl, const int* __restrict__ deg,
    const int* __restrict__ blockSums, int* __restrict__ rowptr,
    int* __restrict__ pos, int N)
{
    int i = blockIdx.x * blockDim.x + threadIdx.x;
    if (i >= N) return;
    int v = incl[i] - deg[i] + blockSums[i >> 9];
    rowptr[i] = v;
    pos[i] = v;
}

// One dst-range eid scatter pass (write locality -> lines fill in L2).
__global__ __launch_bounds__(256) void scatter_pass_kernel(
    const int* __restrict__ dst, int* __restrict__ pos,
    int* __restrict__ eid, int lo, int E)
{
    int e = blockIdx.x * blockDim.x + threadIdx.x;
    if (e >= E) return;
    int d = dst[e];
    if ((unsigned)(d - lo) >= (unsigned)PASS_W) return;
    int p = atomicAdd(&pos[d], 1);
    eid[p] = e;
}

// Wave-per-node rank sort + record materialization (canonical ascending eid).
__global__ __launch_bounds__(256) void ranksort_gather_kernel(
    const int* __restrict__ eid, const int* __restrict__ src,
    const float* __restrict__ ea,
    const int* __restrict__ rowptr, const int* __restrict__ deg,
    int* __restrict__ src_s, __half* __restrict__ ea16, int N)
{
    int wave = threadIdx.x >> 6;
    int lane = threadIdx.x & 63;
    int n = blockIdx.x * 4 + wave;
    if (n >= N) return;
    int s = __builtin_amdgcn_readfirstlane(rowptr[n]);
    int d = __builtin_amdgcn_readfirstlane(deg[n]);

    for (int l = lane; l < d; l += 64) {
        int e = eid[s + l];
        int rank = 0;
        for (int i = 0; i < d; ++i)
            rank += (eid[s + i] < e) ? 1 : 0;
        int p = s + rank;
        src_s[p] = src[e];
        const float4* q = (const float4*)(ea + (size_t)e * EDGE_DIM);
        float4 a = q[0], b = q[1];
        __half2* o = (__half2*)(ea16 + (size_t)p * EDGE_DIM);
        o[0] = __floats2half2_rn(a.x, a.y);
        o[1] = __floats2half2_rn(a.z, a.w);
        o[2] = __floats2half2_rn(b.x, b.y);
        o[3] = __floats2half2_rn(b.z, b.w);
    }
}

// x fp32->fp16 AND all three W -> Wt fp16 transposed, one dispatch.
#define XH_ELEMS (N_NODES * IN_CH)
__global__ __launch_bounds__(256) void cvt_all_kernel(
    const float* __restrict__ x, __half* __restrict__ xh,
    const float* __restrict__ W1, const float* __restrict__ W2,
    const float* __restrict__ W3,
    _Float16* __restrict__ Wt1, _Float16* __restrict__ Wt2,
    _Float16* __restrict__ Wt3)
{
    int idx = blockIdx.x * blockDim.x + threadIdx.x;
    if (idx < XH_ELEMS) { xh[idx] = __float2half(x[idx]); return; }
    idx -= XH_ELEMS;
    if (idx < 128 * IN_CH) {
        int n = idx / IN_CH, k = idx - n * IN_CH;
        Wt1[idx] = (_Float16)W1[k * 128 + n];
        return;
    }
    idx -= 128 * IN_CH;
    if (idx < 128 * HIDDEN) {
        int n = idx / HIDDEN, k = idx - n * HIDDEN;
        Wt2[idx] = (_Float16)W2[k * 128 + n];
        return;
    }
    idx -= 128 * HIDDEN;
    if (idx < 128 * HIDDEN) {
        int n = idx / HIDDEN, k = idx - n * HIDDEN;
        Wt3[idx] = (_Float16)W3[k * 128 + n];
    }
}

// ===========================================================================
// Gather-aggregate: 4 waves/block, one node per wave, 8 edges in flight,
// software-pipelined src-id prefetch (next batch's sids load during current
// batch's compute). Packed-fp16 message math, fp32 acc, canonical order ->
// bit-deterministic.
//   xs[n][j] = h[n][j] + sum_e relu( h[src][j] + (ea@We+be)[j] )
// ===========================================================================
#define BF 8   // edges in flight per wave

__global__ __launch_bounds__(256) void gather_xs128_kernel(
    const __half* __restrict__ h,       // [N,128] fp16
    const int*    __restrict__ src_s,   // [E] CSR order
    const __half* __restrict__ ea16,    // [E,8] fp16 CSR order
    const int*    __restrict__ rowptr,  // [N]
    const int*    __restrict__ deg,     // [N]
    const float*  __restrict__ We,      // [8,128]
    const float*  __restrict__ be,      // [128]
    __half*       __restrict__ xs,      // [N,128] fp16
    int N)
{
    int wave = threadIdx.x >> 6;
    int n    = blockIdx.x * 4 + wave;
    if (n >= N) return;
    int l  = threadIdx.x & 63;  // lane
    int j0 = 2 * l;

    __half2 hw[8];
    #pragma unroll
    for (int k = 0; k < 8; ++k) {
        float2 wv = *(const float2*)&We[k * 128 + j0];
        hw[k] = __floats2half2_rn(wv.x, wv.y);
    }
    float2 bevf = *(const float2*)&be[j0];
    __half2 bev2 = __floats2half2_rn(bevf.x, bevf.y);

    int start = __builtin_amdgcn_readfirstlane(rowptr[n]);
    int dg    = __builtin_amdgcn_readfirstlane(deg[n]);

    float2 hf = __half22float2(*(const __half2*)&h[(size_t)n * 128 + j0]);
    float acc0 = hf.x, acc1 = hf.y;   // self term (eps = 0)

    int nb = dg / BF;                  // full batches
    int base = start;

    int sid[BF];
    if (nb > 0) {
        #pragma unroll
        for (int t = 0; t < BF; ++t)
            sid[t] = __builtin_amdgcn_readfirstlane(src_s[start + t]);
    }

    for (int b = 0; b < nb; ++b, base += BF) {
        // issue random h-row loads for CURRENT batch immediately (sids ready)
        __half2 hraw[BF];
        #pragma unroll
        for (int t = 0; t < BF; ++t)
            hraw[t] = *(const __half2*)&h[(size_t)sid[t] * 128 + j0];

        // prefetch NEXT batch's sids (clamped -> always safe) during compute
        int sidn[BF];
        {
            int nbase = base + BF;
            #pragma unroll
            for (int t = 0; t < BF; ++t) {
                int idx = nbase + t;
                if (idx > N_EDGES - 1) idx = N_EDGES - 1;
                sidn[t] = __builtin_amdgcn_readfirstlane(src_s[idx]);
            }
        }

        int4 eav[BF];                  // uniform 16B edge-attr loads
        #pragma unroll
        for (int t = 0; t < BF; ++t)
            eav[t] = *(const int4*)&ea16[(size_t)(base + t) * 8];

        #pragma unroll
        for (int t = 0; t < BF; ++t) {
            __half2 e01 = u2h(eav[t].x), e23 = u2h(eav[t].y);
            __half2 e45 = u2h(eav[t].z), e67 = u2h(eav[t].w);
            __half2 m = __hfma2(__low2half2(e01),  hw[0], bev2);
            m = __hfma2(__high2half2(e01), hw[1], m);
            m = __hfma2(__low2half2(e23),  hw[2], m);
            m = __hfma2(__high2half2(e23), hw[3], m);
            m = __hfma2(__low2half2(e45),  hw[4], m);
            m = __hfma2(__high2half2(e45), hw[5], m);
            m = __hfma2(__low2half2(e67),  hw[6], m);
            m = __hfma2(__high2half2(e67), hw[7], m);
            m = __hadd2(m, hraw[t]);
            float2 mf = __half22float2(m);
            acc0 += mf.x > 0.0f ? mf.x : 0.0f;
            acc1 += mf.y > 0.0f ? mf.y : 0.0f;
        }

        #pragma unroll
        for (int t = 0; t < BF; ++t) sid[t] = sidn[t];
    }
    // tail (< BF edges), fixed order
    int end = start + dg;
    for (int idx = base; idx < end; ++idx) {
        int s = __builtin_amdgcn_readfirstlane(src_s[idx]);
        __half2 hr = *(const __half2*)&h[(size_t)s * 128 + j0];
        int4 ev = *(const int4*)&ea16[(size_t)idx * 8];
        __half2 e01 = u2h(ev.x), e23 = u2h(ev.y), e45 = u2h(ev.z), e67 = u2h(ev.w);
        __half2 m = __hfma2(__low2half2(e01),  hw[0], bev2);
        m = __hfma2(__high2half2(e01), hw[1], m);
        m = __hfma2(__low2half2(e23),  hw[2], m);
        m = __hfma2(__high2half2(e23), hw[3], m);
        m = __hfma2(__low2half2(e45),  hw[4], m);
        m = __hfma2(__high2half2(e45), hw[5], m);
        m = __hfma2(__low2half2(e67),  hw[6], m);
        m = __hfma2(__high2half2(e67), hw[7], m);
        m = __hadd2(m, hr);
        float2 mf = __half22float2(m);
        acc0 += mf.x > 0.0f ? mf.x : 0.0f;
        acc1 += mf.y > 0.0f ? mf.y : 0.0f;
    }
    *(__half2*)&xs[(size_t)n * 128 + j0] = __floats2half2_rn(acc0, acc1);
}

// D=64: 4 waves/block, one node per wave, 1 feature/lane, same pipelining.
__global__ __launch_bounds__(256) void gather_xs64_kernel(
    const __half* __restrict__ h,       // [N,64] fp16
    const int*    __restrict__ src_s,
    const __half* __restrict__ ea16,    // [E,8] fp16
    const int*    __restrict__ rowptr,
    const int*    __restrict__ deg,
    const float*  __restrict__ We,      // [8,64]
    const float*  __restrict__ be,      // [64]
    __half*       __restrict__ xs,      // [N,64] fp16
    int N)
{
    int wave = threadIdx.x >> 6;
    int n    = blockIdx.x * 4 + wave;
    if (n >= N) return;
    int j = threadIdx.x & 63;

    __half2 w2[4];
    #pragma unroll
    for (int p = 0; p < 4; ++p)
        w2[p] = __floats2half2_rn(We[(2 * p) * 64 + j], We[(2 * p + 1) * 64 + j]);
    float bej = be[j];

    int start = __builtin_amdgcn_readfirstlane(rowptr[n]);
    int dg    = __builtin_amdgcn_readfirstlane(deg[n]);

    float acc = __half2float(h[(size_t)n * 64 + j]);   // self term

    int nb = dg / BF;
    int base = start;

    int sid[BF];
    if (nb > 0) {
        #pragma unroll
        for (int t = 0; t < BF; ++t)
            sid[t] = __builtin_amdgcn_readfirstlane(src_s[start + t]);
    }

    for (int b = 0; b < nb; ++b, base += BF) {
        __half hraw[BF];
        #pragma unroll
        for (int t = 0; t < BF; ++t)
            hraw[t] = h[(size_t)sid[t] * 64 + j];

        int sidn[BF];
        {
            int nbase = base + BF;
            #pragma unroll
            for (int t = 0; t < BF; ++t) {
                int idx = nbase + t;
                if (idx > N_EDGES - 1) idx = N_EDGES - 1;
                sidn[t] = __builtin_amdgcn_readfirstlane(src_s[idx]);
            }
        }

        int4 eav[BF];
        #pragma unroll
        for (int t = 0; t < BF; ++t)
            eav[t] = *(const int4*)&ea16[(size_t)(base + t) * 8];

        #pragma unroll
        for (int t = 0; t < BF; ++t) {
            __half2 d = __hmul2(u2h(eav[t].x), w2[0]);
            d = __hfma2(u2h(eav[t].y), w2[1], d);
            d = __hfma2(u2h(eav[t].z), w2[2], d);
            d = __hfma2(u2h(eav[t].w), w2[3], d);
            float proj = __half2float(__low2half(d)) + __half2float(__high2half(d));
            float m = __half2float(hraw[t]) + proj + bej;
            acc += m > 0.0f ? m : 0.0f;
        }

        #pragma unroll
        for (int t = 0; t < BF; ++t) sid[t] = sidn[t];
    }
    int end = start + dg;
    for (int idx = base; idx < end; ++idx) {
        int s = __builtin_amdgcn_readfirstlane(src_s[idx]);
        __half hr = h[(size_t)s * 64 + j];
        int4 ev = *(const int4*)&ea16[(size_t)idx * 8];
        __half2 d = __hmul2(u2h(ev.x), w2[0]);
        d = __hfma2(u2h(ev.y), w2[1], d);
        d = __hfma2(u2h(ev.z), w2[2], d);
        d = __hfma2(u2h(ev.w), w2[3], d);
        float proj = __half2float(__low2half(d)) + __half2float(__high2half(d));
        float m = __half2float(hr) + proj + bej;
        acc += m > 0.0f ? m : 0.0f;
    }
    xs[(size_t)n * 64 + j] = __float2half(acc);
}

// ===========================================================================
// Node GEMM on matrix cores: out = relu(xs @ W + b), fp16 in/out, fp32 acc.
// One wave = 32 nodes (two 16-row tiles sharing each Wt fragment load).
// ===========================================================================
template<int K>
__global__ __launch_bounds__(256) void node_mfma_kernel(
    const _Float16* __restrict__ xs,   // [N,K] fp16
    const _Float16* __restrict__ Wt,   // [128][K] fp16 (W transposed)
    const float*    __restrict__ b,    // [128]
    _Float16*       __restrict__ out,  // [N,128] fp16
    int N)
{
    int wave  = threadIdx.x >> 6;             // 0..3
    int lane  = threadIdx.x & 63;
    int row16 = lane & 15;
    int quad  = lane >> 4;
    int m0    = (blockIdx.x * 4 + wave) * 32;

    int nA = m0 + row16;        if (nA >= N) nA = N - 1;
    int nB = m0 + 16 + row16;   if (nB >= N) nB = N - 1;

    floatx4 accA[8], accB[8];
    #pragma unroll
    for (int t = 0; t < 8; ++t) { accA[t] = (floatx4)(0.0f); accB[t] = (floatx4)(0.0f); }

    #pragma unroll
    for (int kc = 0; kc < K; kc += 32) {
        half8 a0 = *(const half8*)&xs[(size_t)nA * K + kc + quad * 8];
        half8 a1 = *(const half8*)&xs[(size_t)nB * K + kc + quad * 8];
        #pragma unroll
        for (int t = 0; t < 8; ++t) {
            half8 bf = *(const half8*)&Wt[(size_t)(t * 16 + row16) * K + kc + quad * 8];
            accA[t] = __builtin_amdgcn_mfma_f32_16x16x32_f16(a0, bf, accA[t], 0, 0, 0);
            accB[t] = __builtin_amdgcn_mfma_f32_16x16x32_f16(a1, bf, accB[t], 0, 0, 0);
        }
    }

    #pragma unroll
    for (int t = 0; t < 8; ++t) {
        int col = t * 16 + row16;
        float bj = b[col];
        #pragma unroll
        for (int r = 0; r < 4; ++r) {
            int nodeA = m0 + quad * 4 + r;
            if (nodeA < N) {
                float v = accA[t][r] + bj;
                out[(size_t)nodeA * 128 + col] = (_Float16)(v > 0.0f ? v : 0.0f);
            }
            int nodeB = m0 + 16 + quad * 4 + r;
            if (nodeB < N) {
                float v = accB[t][r] + bj;
                out[(size_t)nodeB * 128 + col] = (_Float16)(v > 0.0f ? v : 0.0f);
            }
        }
    }
}

// ===========================================================================
// Pool: batch sorted -> one block per graph, binary-search range, direct sum.
// ===========================================================================
__global__ __launch_bounds__(128) void pool_kernel(
    const __half* __restrict__ h,      // [N, 128] fp16
    const int*    __restrict__ batch,  // [N] sorted
    float*        __restrict__ out,    // [G, 128]
    int N)
{
    __shared__ int s_lo, s_hi;
    int g = blockIdx.x;
    int j = threadIdx.x;

    if (j == 0) {
        int lo = 0, hi = N;
        while (lo < hi) { int m = (lo + hi) >> 1; if (batch[m] < g) lo = m + 1; else hi = m; }
        s_lo = lo;
        int lo2 = lo, hi2 = N;
        while (lo2 < hi2) { int m = (lo2 + hi2) >> 1; if (batch[m] < g + 1) lo2 = m + 1; else hi2 = m; }
        s_hi = lo2;
    }
    __syncthreads();

    int lo = s_lo, hi = s_hi;
    float acc = 0.0f;
    #pragma unroll 4
    for (int n = lo; n < hi; ++n) {
        acc += __half2float(h[(size_t)n * HIDDEN + j]);
    }
    float c = (float)(hi - lo);
    out[g * HIDDEN + j] = acc / (c > 1.0f ? c : 1.0f);
}

// ===========================================================================
extern "C" void kernel_launch(void* const* d_in, const int* in_sizes, int n_in,
                              void* d_out, int out_size, void* d_ws, size_t ws_size,
                              hipStream_t stream)
{
    const float* x   = (const float*)d_in[0];      // [N, 64]
    const int*   ei  = (const int*)d_in[1];        // [2, E]
    const float* ea  = (const float*)d_in[2];      // [E, 8]
    const int*   bat = (const int*)d_in[3];        // [N]
    const float* W1  = (const float*)d_in[4];
    const float* b1  = (const float*)d_in[5];
    const float* We1 = (const float*)d_in[6];
    const float* be1 = (const float*)d_in[7];
    const float* W2  = (const float*)d_in[8];
    const float* b2  = (const float*)d_in[9];
    const float* We2 = (const float*)d_in[10];
    const float* be2 = (const float*)d_in[11];
    const float* W3  = (const float*)d_in[12];
    const float* b3  = (const float*)d_in[13];
    const float* We3 = (const float*)d_in[14];
    const float* be3 = (const float*)d_in[15];
    float* out = (float*)d_out;

    const int* src = ei;
    const int* dst = ei + N_EDGES;

    // ---------------- workspace layout ----------------
    int* deg       = (int*)d_ws;                             // [N]
    int* rowptr    = deg + N_NODES;                          // [N]
    int* pos       = rowptr + N_NODES;                       // [N]
    int* eid       = pos + N_NODES;                          // [E]
    int* src_s     = eid + N_EDGES;                          // [E]
    int* blockSums = src_s + N_EDGES;                        // [128]
    __half* ea16   = (__half*)(blockSums + 128);             // [E, 8] fp16
    __half* xs     = ea16 + (size_t)N_EDGES * EDGE_DIM;      // [N,128] fp16
    __half* xh     = xs + (size_t)N_NODES * HIDDEN;          // [N, 64] fp16
    __half* h1h    = xh + (size_t)N_NODES * IN_CH;           // [N, 128] fp16
    __half* h2h    = h1h + (size_t)N_NODES * HIDDEN;         // [N, 128] fp16
    _Float16* Wt1  = (_Float16*)(h2h + (size_t)N_NODES * HIDDEN); // [128,64]
    _Float16* Wt2  = Wt1 + 128 * IN_CH;                      // [128,128]
    _Float16* Wt3  = Wt2 + 128 * HIDDEN;                     // [128,128]

    const int BLK = 256;
    const int NB_E = (N_EDGES + BLK - 1) / BLK;
    const int NB_N = (N_NODES + BLK - 1) / BLK;
    const int SCAN_B = (N_NODES + 511) / 512;    // 98
    const int MFMA_B = (N_NODES + 127) / 128;    // 391
    const int WAVE4_B = (N_NODES + 3) / 4;       // 12500 (4 waves/block, 1 node/wave)
    const int CVT_ELEMS = XH_ELEMS + 128 * IN_CH + 2 * 128 * HIDDEN;

    // ---------------- deterministic CSR build ----------------
    hipMemsetAsync(deg, 0, N_NODES * sizeof(int), stream);
    hist_kernel<<<NB_E, BLK, 0, stream>>>(dst, deg, N_EDGES);
    scan1_kernel<<<SCAN_B, 256, 0, stream>>>(deg, pos, blockSums, N_NODES);
    scan2_kernel<<<1, 128, 0, stream>>>(blockSums, SCAN_B);
    scan3_kernel<<<NB_N, BLK, 0, stream>>>(pos, deg, blockSums, rowptr, pos, N_NODES);
    for (int pass = 0; pass < NPASS; ++pass) {
        scatter_pass_kernel<<<NB_E, BLK, 0, stream>>>(
            dst, pos, eid, pass * PASS_W, N_EDGES);
    }
    ranksort_gather_kernel<<<WAVE4_B, BLK, 0, stream>>>(
        eid, src, ea, rowptr, deg, src_s, ea16, N_NODES);
    cvt_all_kernel<<<(CVT_ELEMS + BLK - 1) / BLK, BLK, 0, stream>>>(
        x, xh, W1, W2, W3, Wt1, Wt2, Wt3);

    // ---------------- layer 1 (64 -> 128) ----------------
    gather_xs64_kernel<<<WAVE4_B, BLK, 0, stream>>>(
        xh, src_s, ea16, rowptr, deg, We1, be1, xs, N_NODES);
    node_mfma_kernel<IN_CH><<<MFMA_B, 256, 0, stream>>>(
        (const _Float16*)xs, Wt1, b1, (_Float16*)h1h, N_NODES);

    // ---------------- layer 2 (128 -> 128) ----------------
    gather_xs128_kernel<<<WAVE4_B, BLK, 0, stream>>>(
        h1h, src_s, ea16, rowptr, deg, We2, be2, xs, N_NODES);
    node_mfma_kernel<HIDDEN><<<MFMA_B, 256, 0, stream>>>(
        (const _Float16*)xs, Wt2, b2, (_Float16*)h2h, N_NODES);

    // ---------------- layer 3 (128 -> 128) ----------------
    gather_xs128_kernel<<<WAVE4_B, BLK, 0, stream>>>(
        h2h, src_s, ea16, rowptr, deg, We3, be3, xs, N_NODES);
    node_mfma_kernel<HIDDEN><<<MFMA_B, 256, 0, stream>>>(
        (const _Float16*)xs, Wt3, b3, (_Float16*)h1h, N_NODES);

    // ---------------- global mean pool ----------------
    pool_kernel<<<NUM_GRAPHS, 128, 0, stream>>>(h1h, bat, out, N_NODES);
}

// Round 19
// 428.205 us; speedup vs baseline: 1.0079x; 1.0079x over previous
//
#include <hip/hip_runtime.h>
#include <hip/hip_bf16.h>
#include <hip/hip_fp16.h>

#define N_NODES 50000
#define N_EDGES 800000
#define IN_CH 64
#define EDGE_DIM 8
#define HIDDEN 128
#define NUM_GRAPHS 256
#define NPASS 2
#define PASS_W ((N_NODES + NPASS - 1) / NPASS)   // 25000

typedef __attribute__((ext_vector_type(8))) _Float16 half8;
typedef __attribute__((ext_vector_type(4))) float floatx4;
typedef __attribute__((ext_vector_type(4))) int intx4;

static __device__ __forceinline__ __half2 u2h(int u) {
    union { int i; __half2 h; } cv; cv.i = u; return cv.h;
}
static __device__ __forceinline__ int h2u(__half2 h) {
    union { __half2 h; int i; } cv; cv.h = h; return cv.i;
}
static __device__ __forceinline__ unsigned short h1u(__half h) {
    union { __half h; unsigned short u; } cv; cv.h = h; return cv.u;
}

// ===========================================================================
// CSR build: histogram, scan, 2 dst-range eid-scatter passes (write locality),
// then a wave-per-node RANK sort fused with record materialization.
// ===========================================================================
__global__ __launch_bounds__(256) void hist_kernel(
    const int* __restrict__ dst, int* __restrict__ deg, int E)
{
    int i = blockIdx.x * blockDim.x + threadIdx.x;
    if (i < E) atomicAdd(&deg[dst[i]], 1);
}

__global__ __launch_bounds__(256) void scan1_kernel(
    const int* __restrict__ deg, int* __restrict__ incl,
    int* __restrict__ blockSums, int N)
{
    __shared__ int s[256];
    int b = blockIdx.x, t = threadIdx.x;
    int i0 = b * 512 + 2 * t;
    int a0 = (i0 < N) ? deg[i0] : 0;
    int a1 = (i0 + 1 < N) ? deg[i0 + 1] : 0;
    int ps = a0 + a1;
    s[t] = ps;
    __syncthreads();
    for (int off = 1; off < 256; off <<= 1) {
        int v = (t >= off) ? s[t - off] : 0;
        __syncthreads();
        s[t] += v;
        __syncthreads();
    }
    int exclp = s[t] - ps;
    if (i0 < N)     incl[i0]     = exclp + a0;
    if (i0 + 1 < N) incl[i0 + 1] = exclp + a0 + a1;
    if (t == 255) blockSums[b] = s[255];
}

__global__ __launch_bounds__(128) void scan2_kernel(int* __restrict__ blockSums, int B)
{
    __shared__ int s[128];
    int t = threadIdx.x;
    int v = (t < B) ? blockSums[t] : 0;
    s[t] = v;
    __syncthreads();
    for (int off = 1; off < 128; off <<= 1) {
        int u = (t >= off) ? s[t - off] : 0;
        __syncthreads();
        s[t] += u;
        __syncthreads();
    }
    if (t < B) blockSums[t] = s[t] - v;   // exclusive
}

__global__ __launch_bounds__(256) void scan3_kernel(
    const int* __restrict__ incl, const int* __restrict__ deg,
    const int* __restrict__ blockSums, int* __restrict__ rowptr,
    int* __restrict__ pos, int N)
{
    int i = blockIdx.x * blockDim.x + threadIdx.x;
    if (i >= N) return;
    int v = incl[i] - deg[i] + blockSums[i >> 9];
    rowptr[i] = v;
    pos[i] = v;
}

// One dst-range eid scatter pass (write locality -> lines fill in L2).
__global__ __launch_bounds__(256) void scatter_pass_kernel(
    const int* __restrict__ dst, int* __restrict__ pos,
    int* __restrict__ eid, int lo, int E)
{
    int e = blockIdx.x * blockDim.x + threadIdx.x;
    if (e >= E) return;
    int d = dst[e];
    if ((unsigned)(d - lo) >= (unsigned)PASS_W) return;
    int p = atomicAdd(&pos[d], 1);
    eid[p] = e;
}

// Wave-per-node rank sort + record materialization (canonical ascending eid).
__global__ __launch_bounds__(256) void ranksort_gather_kernel(
    const int* __restrict__ eid, const int* __restrict__ src,
    const float* __restrict__ ea,
    const int* __restrict__ rowptr, const int* __restrict__ deg,
    int* __restrict__ src_s, __half* __restrict__ ea16, int N)
{
    int wave = threadIdx.x >> 6;
    int lane = threadIdx.x & 63;
    int n = blockIdx.x * 4 + wave;
    if (n >= N) return;
    int s = __builtin_amdgcn_readfirstlane(rowptr[n]);
    int d = __builtin_amdgcn_readfirstlane(deg[n]);

    for (int l = lane; l < d; l += 64) {
        int e = eid[s + l];
        int rank = 0;
        for (int i = 0; i < d; ++i)
            rank += (eid[s + i] < e) ? 1 : 0;
        int p = s + rank;
        src_s[p] = src[e];
        const float4* q = (const float4*)(ea + (size_t)e * EDGE_DIM);
        float4 a = q[0], b = q[1];
        __half2* o = (__half2*)(ea16 + (size_t)p * EDGE_DIM);
        o[0] = __floats2half2_rn(a.x, a.y);
        o[1] = __floats2half2_rn(a.z, a.w);
        o[2] = __floats2half2_rn(b.x, b.y);
        o[3] = __floats2half2_rn(b.z, b.w);
    }
}

// x fp32->fp16 AND all three W -> Wt fp16 transposed, one dispatch.
#define XH_ELEMS (N_NODES * IN_CH)
__global__ __launch_bounds__(256) void cvt_all_kernel(
    const float* __restrict__ x, __half* __restrict__ xh,
    const float* __restrict__ W1, const float* __restrict__ W2,
    const float* __restrict__ W3,
    _Float16* __restrict__ Wt1, _Float16* __restrict__ Wt2,
    _Float16* __restrict__ Wt3)
{
    int idx = blockIdx.x * blockDim.x + threadIdx.x;
    if (idx < XH_ELEMS) { xh[idx] = __float2half(x[idx]); return; }
    idx -= XH_ELEMS;
    if (idx < 128 * IN_CH) {
        int n = idx / IN_CH, k = idx - n * IN_CH;
        Wt1[idx] = (_Float16)W1[k * 128 + n];
        return;
    }
    idx -= 128 * IN_CH;
    if (idx < 128 * HIDDEN) {
        int n = idx / HIDDEN, k = idx - n * HIDDEN;
        Wt2[idx] = (_Float16)W2[k * 128 + n];
        return;
    }
    idx -= 128 * HIDDEN;
    if (idx < 128 * HIDDEN) {
        int n = idx / HIDDEN, k = idx - n * HIDDEN;
        Wt3[idx] = (_Float16)W3[k * 128 + n];
    }
}

// ===========================================================================
// Gather-aggregate: 4 waves/block, one node per wave, 8 edges in flight.
// Streaming traffic (src_s, ea16 reads; xs writes) is NONTEMPORAL so L2
// retains the randomly re-read h rows. Packed-fp16 message math, fp32 acc,
// canonical order -> bit-deterministic.
//   xs[n][j] = h[n][j] + sum_e relu( h[src][j] + (ea@We+be)[j] )
// ===========================================================================
#define BF 8   // edges in flight per wave

__global__ __launch_bounds__(256) void gather_xs128_kernel(
    const __half* __restrict__ h,       // [N,128] fp16
    const int*    __restrict__ src_s,   // [E] CSR order
    const __half* __restrict__ ea16,    // [E,8] fp16 CSR order
    const int*    __restrict__ rowptr,  // [N]
    const int*    __restrict__ deg,     // [N]
    const float*  __restrict__ We,      // [8,128]
    const float*  __restrict__ be,      // [128]
    __half*       __restrict__ xs,      // [N,128] fp16
    int N)
{
    int wave = threadIdx.x >> 6;
    int n    = blockIdx.x * 4 + wave;
    if (n >= N) return;
    int l  = threadIdx.x & 63;  // lane
    int j0 = 2 * l;

    __half2 hw[8];
    #pragma unroll
    for (int k = 0; k < 8; ++k) {
        float2 wv = *(const float2*)&We[k * 128 + j0];
        hw[k] = __floats2half2_rn(wv.x, wv.y);
    }
    float2 bevf = *(const float2*)&be[j0];
    __half2 bev2 = __floats2half2_rn(bevf.x, bevf.y);

    int start = __builtin_amdgcn_readfirstlane(rowptr[n]);
    int dg    = __builtin_amdgcn_readfirstlane(deg[n]);

    float2 hf = __half22float2(*(const __half2*)&h[(size_t)n * 128 + j0]);
    float acc0 = hf.x, acc1 = hf.y;   // self term (eps = 0)

    int nb = dg / BF;                  // full batches
    int base = start;
    for (int b = 0; b < nb; ++b, base += BF) {
        int sid[BF];
        #pragma unroll
        for (int t = 0; t < BF; ++t)
            sid[t] = __builtin_amdgcn_readfirstlane(
                __builtin_nontemporal_load(&src_s[base + t]));
        __half2 hraw[BF];              // random 4B/lane loads (cached - hot)
        #pragma unroll
        for (int t = 0; t < BF; ++t)
            hraw[t] = *(const __half2*)&h[(size_t)sid[t] * 128 + j0];
        intx4 eav[BF];                 // uniform streaming loads - nontemporal
        #pragma unroll
        for (int t = 0; t < BF; ++t)
            eav[t] = __builtin_nontemporal_load(
                (const intx4*)&ea16[(size_t)(base + t) * 8]);

        #pragma unroll
        for (int t = 0; t < BF; ++t) {
            __half2 e01 = u2h(eav[t].x), e23 = u2h(eav[t].y);
            __half2 e45 = u2h(eav[t].z), e67 = u2h(eav[t].w);
            __half2 m = __hfma2(__low2half2(e01),  hw[0], bev2);
            m = __hfma2(__high2half2(e01), hw[1], m);
            m = __hfma2(__low2half2(e23),  hw[2], m);
            m = __hfma2(__high2half2(e23), hw[3], m);
            m = __hfma2(__low2half2(e45),  hw[4], m);
            m = __hfma2(__high2half2(e45), hw[5], m);
            m = __hfma2(__low2half2(e67),  hw[6], m);
            m = __hfma2(__high2half2(e67), hw[7], m);
            m = __hadd2(m, hraw[t]);
            float2 mf = __half22float2(m);
            acc0 += mf.x > 0.0f ? mf.x : 0.0f;
            acc1 += mf.y > 0.0f ? mf.y : 0.0f;
        }
    }
    // tail (< BF edges), fixed order
    int end = start + dg;
    for (int idx = base; idx < end; ++idx) {
        int s = __builtin_amdgcn_readfirstlane(src_s[idx]);
        __half2 hr = *(const __half2*)&h[(size_t)s * 128 + j0];
        intx4 ev = __builtin_nontemporal_load((const intx4*)&ea16[(size_t)idx * 8]);
        __half2 e01 = u2h(ev.x), e23 = u2h(ev.y), e45 = u2h(ev.z), e67 = u2h(ev.w);
        __half2 m = __hfma2(__low2half2(e01),  hw[0], bev2);
        m = __hfma2(__high2half2(e01), hw[1], m);
        m = __hfma2(__low2half2(e23),  hw[2], m);
        m = __hfma2(__high2half2(e23), hw[3], m);
        m = __hfma2(__low2half2(e45),  hw[4], m);
        m = __hfma2(__high2half2(e45), hw[5], m);
        m = __hfma2(__low2half2(e67),  hw[6], m);
        m = __hfma2(__high2half2(e67), hw[7], m);
        m = __hadd2(m, hr);
        float2 mf = __half22float2(m);
        acc0 += mf.x > 0.0f ? mf.x : 0.0f;
        acc1 += mf.y > 0.0f ? mf.y : 0.0f;
    }
    __builtin_nontemporal_store(h2u(__floats2half2_rn(acc0, acc1)),
                                (int*)&xs[(size_t)n * 128 + j0]);
}

// D=64: 4 waves/block, one node per wave, 1 feature/lane.
__global__ __launch_bounds__(256) void gather_xs64_kernel(
    const __half* __restrict__ h,       // [N,64] fp16
    const int*    __restrict__ src_s,
    const __half* __restrict__ ea16,    // [E,8] fp16
    const int*    __restrict__ rowptr,
    const int*    __restrict__ deg,
    const float*  __restrict__ We,      // [8,64]
    const float*  __restrict__ be,      // [64]
    __half*       __restrict__ xs,      // [N,64] fp16
    int N)
{
    int wave = threadIdx.x >> 6;
    int n    = blockIdx.x * 4 + wave;
    if (n >= N) return;
    int j = threadIdx.x & 63;

    __half2 w2[4];
    #pragma unroll
    for (int p = 0; p < 4; ++p)
        w2[p] = __floats2half2_rn(We[(2 * p) * 64 + j], We[(2 * p + 1) * 64 + j]);
    float bej = be[j];

    int start = __builtin_amdgcn_readfirstlane(rowptr[n]);
    int dg    = __builtin_amdgcn_readfirstlane(deg[n]);

    float acc = __half2float(h[(size_t)n * 64 + j]);   // self term

    int nb = dg / BF;
    int base = start;
    for (int b = 0; b < nb; ++b, base += BF) {
        int sid[BF];
        #pragma unroll
        for (int t = 0; t < BF; ++t)
            sid[t] = __builtin_amdgcn_readfirstlane(
                __builtin_nontemporal_load(&src_s[base + t]));
        __half hraw[BF];
        #pragma unroll
        for (int t = 0; t < BF; ++t)
            hraw[t] = h[(size_t)sid[t] * 64 + j];
        intx4 eav[BF];
        #pragma unroll
        for (int t = 0; t < BF; ++t)
            eav[t] = __builtin_nontemporal_load(
                (const intx4*)&ea16[(size_t)(base + t) * 8]);

        #pragma unroll
        for (int t = 0; t < BF; ++t) {
            __half2 d = __hmul2(u2h(eav[t].x), w2[0]);
            d = __hfma2(u2h(eav[t].y), w2[1], d);
            d = __hfma2(u2h(eav[t].z), w2[2], d);
            d = __hfma2(u2h(eav[t].w), w2[3], d);
            float proj = __half2float(__low2half(d)) + __half2float(__high2half(d));
            float m = __half2float(hraw[t]) + proj + bej;
            acc += m > 0.0f ? m : 0.0f;
        }
    }
    int end = start + dg;
    for (int idx = base; idx < end; ++idx) {
        int s = __builtin_amdgcn_readfirstlane(src_s[idx]);
        __half hr = h[(size_t)s * 64 + j];
        intx4 ev = __builtin_nontemporal_load((const intx4*)&ea16[(size_t)idx * 8]);
        __half2 d = __hmul2(u2h(ev.x), w2[0]);
        d = __hfma2(u2h(ev.y), w2[1], d);
        d = __hfma2(u2h(ev.z), w2[2], d);
        d = __hfma2(u2h(ev.w), w2[3], d);
        float proj = __half2float(__low2half(d)) + __half2float(__high2half(d));
        float m = __half2float(hr) + proj + bej;
        acc += m > 0.0f ? m : 0.0f;
    }
    __builtin_nontemporal_store(h1u(__float2half(acc)),
                                (unsigned short*)&xs[(size_t)n * 64 + j]);
}

// ===========================================================================
// Node GEMM on matrix cores: out = relu(xs @ W + b), fp16 in/out, fp32 acc.
// xs is read-once -> nontemporal loads; Wt stays cached (hot).
// One wave = 32 nodes (two 16-row tiles sharing each Wt fragment load).
// ===========================================================================
template<int K>
__global__ __launch_bounds__(256) void node_mfma_kernel(
    const _Float16* __restrict__ xs,   // [N,K] fp16
    const _Float16* __restrict__ Wt,   // [128][K] fp16 (W transposed)
    const float*    __restrict__ b,    // [128]
    _Float16*       __restrict__ out,  // [N,128] fp16
    int N)
{
    int wave  = threadIdx.x >> 6;             // 0..3
    int lane  = threadIdx.x & 63;
    int row16 = lane & 15;
    int quad  = lane >> 4;
    int m0    = (blockIdx.x * 4 + wave) * 32;

    int nA = m0 + row16;        if (nA >= N) nA = N - 1;
    int nB = m0 + 16 + row16;   if (nB >= N) nB = N - 1;

    floatx4 accA[8], accB[8];
    #pragma unroll
    for (int t = 0; t < 8; ++t) { accA[t] = (floatx4)(0.0f); accB[t] = (floatx4)(0.0f); }

    #pragma unroll
    for (int kc = 0; kc < K; kc += 32) {
        half8 a0 = __builtin_nontemporal_load((const half8*)&xs[(size_t)nA * K + kc + quad * 8]);
        half8 a1 = __builtin_nontemporal_load((const half8*)&xs[(size_t)nB * K + kc + quad * 8]);
        #pragma unroll
        for (int t = 0; t < 8; ++t) {
            half8 bf = *(const half8*)&Wt[(size_t)(t * 16 + row16) * K + kc + quad * 8];
            accA[t] = __builtin_amdgcn_mfma_f32_16x16x32_f16(a0, bf, accA[t], 0, 0, 0);
            accB[t] = __builtin_amdgcn_mfma_f32_16x16x32_f16(a1, bf, accB[t], 0, 0, 0);
        }
    }

    #pragma unroll
    for (int t = 0; t < 8; ++t) {
        int col = t * 16 + row16;
        float bj = b[col];
        #pragma unroll
        for (int r = 0; r < 4; ++r) {
            int nodeA = m0 + quad * 4 + r;
            if (nodeA < N) {
                float v = accA[t][r] + bj;
                out[(size_t)nodeA * 128 + col] = (_Float16)(v > 0.0f ? v : 0.0f);
            }
            int nodeB = m0 + 16 + quad * 4 + r;
            if (nodeB < N) {
                float v = accB[t][r] + bj;
                out[(size_t)nodeB * 128 + col] = (_Float16)(v > 0.0f ? v : 0.0f);
            }
        }
    }
}

// ===========================================================================
// Pool: batch sorted -> one block per graph, binary-search range, direct sum.
// ===========================================================================
__global__ __launch_bounds__(128) void pool_kernel(
    const __half* __restrict__ h,      // [N, 128] fp16
    const int*    __restrict__ batch,  // [N] sorted
    float*        __restrict__ out,    // [G, 128]
    int N)
{
    __shared__ int s_lo, s_hi;
    int g = blockIdx.x;
    int j = threadIdx.x;

    if (j == 0) {
        int lo = 0, hi = N;
        while (lo < hi) { int m = (lo + hi) >> 1; if (batch[m] < g) lo = m + 1; else hi = m; }
        s_lo = lo;
        int lo2 = lo, hi2 = N;
        while (lo2 < hi2) { int m = (lo2 + hi2) >> 1; if (batch[m] < g + 1) lo2 = m + 1; else hi2 = m; }
        s_hi = lo2;
    }
    __syncthreads();

    int lo = s_lo, hi = s_hi;
    float acc = 0.0f;
    #pragma unroll 4
    for (int n = lo; n < hi; ++n) {
        acc += __half2float(h[(size_t)n * HIDDEN + j]);
    }
    float c = (float)(hi - lo);
    out[g * HIDDEN + j] = acc / (c > 1.0f ? c : 1.0f);
}

// ===========================================================================
extern "C" void kernel_launch(void* const* d_in, const int* in_sizes, int n_in,
                              void* d_out, int out_size, void* d_ws, size_t ws_size,
                              hipStream_t stream)
{
    const float* x   = (const float*)d_in[0];      // [N, 64]
    const int*   ei  = (const int*)d_in[1];        // [2, E]
    const float* ea  = (const float*)d_in[2];      // [E, 8]
    const int*   bat = (const int*)d_in[3];        // [N]
    const float* W1  = (const float*)d_in[4];
    const float* b1  = (const float*)d_in[5];
    const float* We1 = (const float*)d_in[6];
    const float* be1 = (const float*)d_in[7];
    const float* W2  = (const float*)d_in[8];
    const float* b2  = (const float*)d_in[9];
    const float* We2 = (const float*)d_in[10];
    const float* be2 = (const float*)d_in[11];
    const float* W3  = (const float*)d_in[12];
    const float* b3  = (const float*)d_in[13];
    const float* We3 = (const float*)d_in[14];
    const float* be3 = (const float*)d_in[15];
    float* out = (float*)d_out;

    const int* src = ei;
    const int* dst = ei + N_EDGES;

    // ---------------- workspace layout ----------------
    int* deg       = (int*)d_ws;                             // [N]
    int* rowptr    = deg + N_NODES;                          // [N]
    int* pos       = rowptr + N_NODES;                       // [N]
    int* eid       = pos + N_NODES;                          // [E]
    int* src_s     = eid + N_EDGES;                          // [E]
    int* blockSums = src_s + N_EDGES;                        // [128]
    __half* ea16   = (__half*)(blockSums + 128);             // [E, 8] fp16
    __half* xs     = ea16 + (size_t)N_EDGES * EDGE_DIM;      // [N,128] fp16
    __half* xh     = xs + (size_t)N_NODES * HIDDEN;          // [N, 64] fp16
    __half* h1h    = xh + (size_t)N_NODES * IN_CH;           // [N, 128] fp16
    __half* h2h    = h1h + (size_t)N_NODES * HIDDEN;         // [N, 128] fp16
    _Float16* Wt1  = (_Float16*)(h2h + (size_t)N_NODES * HIDDEN); // [128,64]
    _Float16* Wt2  = Wt1 + 128 * IN_CH;                      // [128,128]
    _Float16* Wt3  = Wt2 + 128 * HIDDEN;                     // [128,128]

    const int BLK = 256;
    const int NB_E = (N_EDGES + BLK - 1) / BLK;
    const int NB_N = (N_NODES + BLK - 1) / BLK;
    const int SCAN_B = (N_NODES + 511) / 512;    // 98
    const int MFMA_B = (N_NODES + 127) / 128;    // 391
    const int WAVE4_B = (N_NODES + 3) / 4;       // 12500 (4 waves/block, 1 node/wave)
    const int CVT_ELEMS = XH_ELEMS + 128 * IN_CH + 2 * 128 * HIDDEN;

    // ---------------- deterministic CSR build ----------------
    (void)hipMemsetAsync(deg, 0, N_NODES * sizeof(int), stream);
    hist_kernel<<<NB_E, BLK, 0, stream>>>(dst, deg, N_EDGES);
    scan1_kernel<<<SCAN_B, 256, 0, stream>>>(deg, pos, blockSums, N_NODES);
    scan2_kernel<<<1, 128, 0, stream>>>(blockSums, SCAN_B);
    scan3_kernel<<<NB_N, BLK, 0, stream>>>(pos, deg, blockSums, rowptr, pos, N_NODES);
    for (int pass = 0; pass < NPASS; ++pass) {
        scatter_pass_kernel<<<NB_E, BLK, 0, stream>>>(
            dst, pos, eid, pass * PASS_W, N_EDGES);
    }
    ranksort_gather_kernel<<<WAVE4_B, BLK, 0, stream>>>(
        eid, src, ea, rowptr, deg, src_s, ea16, N_NODES);
    cvt_all_kernel<<<(CVT_ELEMS + BLK - 1) / BLK, BLK, 0, stream>>>(
        x, xh, W1, W2, W3, Wt1, Wt2, Wt3);

    // ---------------- layer 1 (64 -> 128) ----------------
    gather_xs64_kernel<<<WAVE4_B, BLK, 0, stream>>>(
        xh, src_s, ea16, rowptr, deg, We1, be1, xs, N_NODES);
    node_mfma_kernel<IN_CH><<<MFMA_B, 256, 0, stream>>>(
        (const _Float16*)xs, Wt1, b1, (_Float16*)h1h, N_NODES);

    // ---------------- layer 2 (128 -> 128) ----------------
    gather_xs128_kernel<<<WAVE4_B, BLK, 0, stream>>>(
        h1h, src_s, ea16, rowptr, deg, We2, be2, xs, N_NODES);
    node_mfma_kernel<HIDDEN><<<MFMA_B, 256, 0, stream>>>(
        (const _Float16*)xs, Wt2, b2, (_Float16*)h2h, N_NODES);

    // ---------------- layer 3 (128 -> 128) ----------------
    gather_xs128_kernel<<<WAVE4_B, BLK, 0, stream>>>(
        h2h, src_s, ea16, rowptr, deg, We3, be3, xs, N_NODES);
    node_mfma_kernel<HIDDEN><<<MFMA_B, 256, 0, stream>>>(
        (const _Float16*)xs, Wt3, b3, (_Float16*)h1h, N_NODES);

    // ---------------- global mean pool ----------------
    pool_kernel<<<NUM_GRAPHS, 128, 0, stream>>>(h1h, bat, out, N_NODES);
}